// Round 1
// baseline (595.852 us; speedup 1.0000x reference)
//
#include <hip/hip_runtime.h>
#include <hip/hip_bf16.h>
#include <stdint.h>

using bf16x8 = __attribute__((ext_vector_type(8))) __bf16;
using bf16x4 = __attribute__((ext_vector_type(4))) __bf16;
using f32x4  = __attribute__((ext_vector_type(4))) float;

typedef const uint32_t __attribute__((address_space(1)))* gas_ptr;
typedef uint32_t __attribute__((address_space(3)))* las_ptr;

__device__ __forceinline__ void load_lds16(const void* g, void* l) {
    __builtin_amdgcn_global_load_lds((gas_ptr)g, (las_ptr)l, 16, 0, 0);
}

// cprelu post-normalization constants (PRELU_INIT = 0.25)
#define PM  0.29920671030107454f
#define PIS 1.5046096f
#define RHALF 0.70710678118654752f

// ---------------------------------------------------------------- k_prep
// Pad + convert weights to bf16 into workspace:
// W1p[96][64], W2p[112][96], WMp[128][128], WSp[128][64]; zeros in pad.
__global__ __launch_bounds__(256) void k_prep(const float* __restrict__ w1,
                                              const float* __restrict__ w2,
                                              const float* __restrict__ wm,
                                              const float* __restrict__ wsw,
                                              __bf16* __restrict__ W1p,
                                              __bf16* __restrict__ W2p,
                                              __bf16* __restrict__ WMp,
                                              __bf16* __restrict__ WSp)
{
    const int id = blockIdx.x * 256 + threadIdx.x;
    const int stride = gridDim.x * 256;
    for (int i = id; i < 96 * 64; i += stride) {
        int oc = i >> 6, ic = i & 63;
        W1p[i] = (__bf16)((oc < 83) ? w1[oc * 64 + ic] : 0.f);
    }
    for (int i = id; i < 112 * 96; i += stride) {
        int oc = i / 96, ic = i % 96;
        W2p[i] = (__bf16)((oc < 102 && ic < 83) ? w2[oc * 83 + ic] : 0.f);
    }
    for (int i = id; i < 128 * 128; i += stride) {
        int oc = i >> 7, ic = i & 127;
        WMp[i] = (__bf16)((ic < 102) ? wm[oc * 102 + ic] : 0.f);
    }
    for (int i = id; i < 128 * 64; i += stride) {
        WSp[i] = (__bf16)wsw[i];
    }
}

// ---------------------------------------------------------------- k_argmax
// Per conn row: find max, store ALL indices equal to max (ties kept, cap 16).
__global__ __launch_bounds__(256) void k_argmax(const float* __restrict__ conn,
                                                int* __restrict__ cnt,
                                                int* __restrict__ idx)
{
    const int o = blockIdx.x;
    const float* row = conn + (size_t)o * 8192;
    float m = -1e30f;
    for (int i = threadIdx.x; i < 8192; i += 256) m = fmaxf(m, row[i]);
#pragma unroll
    for (int off = 32; off > 0; off >>= 1) m = fmaxf(m, __shfl_down(m, off, 64));
    __shared__ float wmax[4];
    __shared__ int scnt;
    if ((threadIdx.x & 63) == 0) wmax[threadIdx.x >> 6] = m;
    if (threadIdx.x == 0) scnt = 0;
    __syncthreads();
    const float rmax = fmaxf(fmaxf(wmax[0], wmax[1]), fmaxf(wmax[2], wmax[3]));
    for (int i = threadIdx.x; i < 8192; i += 256) {
        if (row[i] >= rmax) {
            int p = atomicAdd(&scnt, 1);
            if (p < 16) idx[o * 16 + p] = i;
        }
    }
    __syncthreads();
    if (threadIdx.x == 0) cnt[o] = scnt < 16 ? scnt : 16;
}

// ---------------------------------------------------------------- k_chain
// One block = (b, 128-position tile). Fused MFMA GEMMs:
//   S  = WS*X + bs            -> s_t[b][pos][c] bf16  (gather-friendly)
//   H1 = cprelu(W1*X + b1)    -> LDS (transposed, stride 104)
//   H2 = cprelu(W2*H1 + b2)   -> LDS (stride 136, reuses X buffer)
//   H3 = WM*H2 + bm           -> h3[(b*128+oc)][pos] bf16 (A of big GEMM)
// Weights read as bf16x8 frags straight from global (L1/L2-hot, padded).
template<int KS>
__device__ __forceinline__ f32x4 mfma_tile(const __bf16* __restrict__ W, int wstride, int mt,
                                           const __bf16* B, int bstride, int nt, int lane)
{
    f32x4 acc = {0.f, 0.f, 0.f, 0.f};
    const int l15 = lane & 15;
    const int kg  = (lane >> 4) << 3;
    const __bf16* wp = W + (mt * 16 + l15) * wstride + kg;
    const __bf16* bp = B + (nt * 16 + l15) * bstride + kg;
#pragma unroll
    for (int ks = 0; ks < KS; ks++) {
        bf16x8 av = *(const bf16x8*)(wp + ks * 32);
        bf16x8 bv = *(const bf16x8*)(bp + ks * 32);
        acc = __builtin_amdgcn_mfma_f32_16x16x32_bf16(av, bv, acc, 0, 0, 0);
    }
    return acc;
}

__global__ __launch_bounds__(256) void k_chain(
    const float* __restrict__ x,
    const float* __restrict__ b1, const float* __restrict__ p1,
    const float* __restrict__ b2, const float* __restrict__ p2,
    const float* __restrict__ bm, const float* __restrict__ bs,
    const __bf16* __restrict__ W1p, const __bf16* __restrict__ W2p,
    const __bf16* __restrict__ WMp, const __bf16* __restrict__ WSp,
    __bf16* __restrict__ h3, __bf16* __restrict__ s_t)
{
    __shared__ __bf16 buf0[128 * 136];   // Xt (stride 72) then H2t (stride 136)
    __shared__ __bf16 H1t[128 * 104];    // stride 104 (K padded to 96 + bank pad)
    __shared__ float  bl[672];
    float* b1l = bl;       float* p1l = bl + 96;
    float* b2l = bl + 192; float* p2l = bl + 304;
    float* bml = bl + 416; float* bsl = bl + 544;

    const int t = threadIdx.x, lane = t & 63, wid = t >> 6;
    const int b = blockIdx.y;
    const int p0 = blockIdx.x * 128;

    for (int i = t; i < 96; i += 256)  { b1l[i] = (i < 83)  ? b1[i] : 0.f; p1l[i] = (i < 83)  ? p1[i] : 0.f; }
    for (int i = t; i < 112; i += 256) { b2l[i] = (i < 102) ? b2[i] : 0.f; p2l[i] = (i < 102) ? p2[i] : 0.f; }
    for (int i = t; i < 128; i += 256) { bml[i] = bm[i]; bsl[i] = bs[i]; }

    // stage X^T: Xt[pos][c] (bf16, stride 72 for 16B alignment + bank spread)
    {
        const int p = t & 127;
        const int chalf = t >> 7;
#pragma unroll 4
        for (int it = 0; it < 32; it++) {
            int c = it * 2 + chalf;
            buf0[p * 72 + c] = (__bf16)x[((size_t)b * 64 + c) * 8192 + p0 + p];
        }
    }
    __syncthreads();

    const int quad4 = (lane >> 4) << 2;
    const int l15 = lane & 15;

    // shortcut S = WS*X + bs
    for (int tt = wid; tt < 64; tt += 4) {
        int mt = tt >> 3, nt = tt & 7;
        f32x4 a = mfma_tile<2>(WSp, 64, mt, buf0, 72, nt, lane);
        int ocb = mt * 16 + quad4;
        int pos = nt * 16 + l15;
        bf16x4 ov;
#pragma unroll
        for (int r = 0; r < 4; r++) ov[r] = (__bf16)(a[r] + bsl[ocb + r]);
        *(bf16x4*)(s_t + ((size_t)b * 8192 + p0 + pos) * 128 + ocb) = ov;
    }
    // H1 = cprelu(W1*X + b1)
    for (int tt = wid; tt < 48; tt += 4) {
        int mt = tt / 8, nt = tt % 8;
        f32x4 a = mfma_tile<2>(W1p, 64, mt, buf0, 72, nt, lane);
        int ocb = mt * 16 + quad4;
        int pos = nt * 16 + l15;
        bf16x4 ov;
#pragma unroll
        for (int r = 0; r < 4; r++) {
            float v = a[r] + b1l[ocb + r];
            v = (v >= 0.f) ? v : v * p1l[ocb + r];
            ov[r] = (__bf16)((v - PM) * PIS);
        }
        *(bf16x4*)(&H1t[pos * 104 + ocb]) = ov;
    }
    __syncthreads();

    // H2 = cprelu(W2*H1 + b2), into buf0 (Xt is dead)
    for (int tt = wid; tt < 56; tt += 4) {
        int mt = tt / 8, nt = tt % 8;
        f32x4 a = mfma_tile<3>(W2p, 96, mt, H1t, 104, nt, lane);
        int ocb = mt * 16 + quad4;
        int pos = nt * 16 + l15;
        bf16x4 ov;
#pragma unroll
        for (int r = 0; r < 4; r++) {
            float v = a[r] + b2l[ocb + r];
            v = (v >= 0.f) ? v : v * p2l[ocb + r];
            ov[r] = (__bf16)((v - PM) * PIS);
        }
        *(bf16x4*)(&buf0[pos * 136 + ocb]) = ov;
    }
    // zero H2 pad channels 112..127 (read by stage-3 K-steps; WM pad is zero
    // but 0*NaN garbage would poison — so clear explicitly)
    for (int i = t; i < 128 * 16; i += 256) {
        int pos = i >> 4, c = 112 + (i & 15);
        buf0[pos * 136 + c] = (__bf16)0.f;
    }
    __syncthreads();

    // H3 = WM*H2 + bm -> global (K-contiguous rows for the big GEMM)
    for (int tt = wid; tt < 64; tt += 4) {
        int mt = tt >> 3, nt = tt & 7;
        f32x4 a = mfma_tile<4>(WMp, 128, mt, buf0, 136, nt, lane);
        int ocb = mt * 16 + quad4;
        int pos = nt * 16 + l15;
#pragma unroll
        for (int r = 0; r < 4; r++)
            h3[((size_t)b * 128 + ocb + r) * 8192 + p0 + pos] = (__bf16)(a[r] + bml[ocb + r]);
    }
}

// ---------------------------------------------------------------- k_gemm
// C[M=2048,N=4096] = h3[M,K=8192](bf16) x conn[N,K](fp32, cvt->bf16 in staging)
// 128x128 block tile, BK=32, 4 waves (2x2 of 64x64), 16x16x32 bf16 MFMA.
// A staged via global_load_lds width-16; B through registers with cvt.
__global__ __launch_bounds__(256) void k_gemm(const __bf16* __restrict__ A,
                                              const float* __restrict__ Bf,
                                              float* __restrict__ C)
{
    __shared__ __bf16 la[128 * 32];
    __shared__ __bf16 lb[128 * 32];
    const int t = threadIdx.x;
    const int lane = t & 63;
    const int wid = t >> 6;
    const int tM = blockIdx.y * 128;
    const int tN = blockIdx.x * 128;
    const int wm2 = (wid & 1) * 64;
    const int wn2 = (wid >> 1) * 64;

    f32x4 acc[4][4];
    const f32x4 zero = {0.f, 0.f, 0.f, 0.f};
#pragma unroll
    for (int i = 0; i < 4; i++)
#pragma unroll
        for (int j = 0; j < 4; j++) acc[i][j] = zero;

    const __bf16* Ab = A + (size_t)tM * 8192;
    const float*  Bb = Bf + (size_t)tN * 8192;
    const int ar = t >> 2;          // A tile row for issue 0 (rows 0..63)
    const int ak = (t & 3) * 8;     // bf16 k-offset within row
    const int l15 = lane & 15;
    const int kg8 = (lane >> 4) * 8;

    for (int kt = 0; kt < 8192; kt += 32) {
        // A tile: 128 rows x 32 bf16 = 8KB, 2 issues of 256 lanes x 16B
        load_lds16(Ab + (size_t)ar * 8192 + kt + ak, la + t * 8);
        load_lds16(Ab + (size_t)(64 + ar) * 8192 + kt + ak, la + 2048 + t * 8);
        // B tile: 128 rows x 32 fp32 -> bf16, 4 issues of float4/thread
#pragma unroll
        for (int q = 0; q < 4; q++) {
            int lin = q * 256 + t;
            int n = lin >> 3;
            int kf = (lin & 7) * 4;
            float4 v = *(const float4*)(Bb + (size_t)n * 8192 + kt + kf);
            bf16x4 wv;
            wv[0] = (__bf16)v.x; wv[1] = (__bf16)v.y;
            wv[2] = (__bf16)v.z; wv[3] = (__bf16)v.w;
            *(bf16x4*)(lb + lin * 4) = wv;
        }
        __syncthreads();
        bf16x8 af[4], bfr[4];
#pragma unroll
        for (int i = 0; i < 4; i++) af[i]  = *(const bf16x8*)(la + (wm2 + i * 16 + l15) * 32 + kg8);
#pragma unroll
        for (int j = 0; j < 4; j++) bfr[j] = *(const bf16x8*)(lb + (wn2 + j * 16 + l15) * 32 + kg8);
#pragma unroll
        for (int i = 0; i < 4; i++)
#pragma unroll
            for (int j = 0; j < 4; j++)
                acc[i][j] = __builtin_amdgcn_mfma_f32_16x16x32_bf16(af[i], bfr[j], acc[i][j], 0, 0, 0);
        __syncthreads();
    }

    const int quad4 = (lane >> 4) * 4;
#pragma unroll
    for (int i = 0; i < 4; i++) {
        int gm = tM + wm2 + i * 16 + quad4;
#pragma unroll
        for (int j = 0; j < 4; j++) {
            int gn = tN + wn2 + j * 16 + l15;
#pragma unroll
            for (int r = 0; r < 4; r++)
                C[(size_t)(gm + r) * 4096 + gn] = acc[i][j][r];
        }
    }
}

// ---------------------------------------------------------------- k_combine
// out[b][c][o] = sqrt(.5)*pooled_shortcut + sqrt(.5)*cprelu(res_pre, p3)
// pooled_shortcut = sum over tied-argmax i of s_t[b][i][c]
__global__ __launch_bounds__(256) void k_combine(float* __restrict__ out,
                                                 const __bf16* __restrict__ s_t,
                                                 const int* __restrict__ idx,
                                                 const int* __restrict__ cnt,
                                                 const float* __restrict__ p3)
{
    __shared__ float sp[64][133];
    const int b = blockIdx.y;
    const int o0 = blockIdx.x * 64;
    const int t = threadIdx.x;

    // phase 1: gather pooled shortcut rows into LDS
    {
        const int ol = t >> 2;       // 0..63
        const int part = t & 3;      // 32 channels each
        const int o = o0 + ol;
        const int n = cnt[o];
        float acc[32];
#pragma unroll
        for (int j = 0; j < 32; j++) acc[j] = 0.f;
        for (int k = 0; k < n; k++) {
            const int i = idx[o * 16 + k];
            const __bf16* row = s_t + ((size_t)b * 8192 + i) * 128 + part * 32;
#pragma unroll
            for (int j = 0; j < 32; j += 8) {
                bf16x8 v = *(const bf16x8*)(row + j);
#pragma unroll
                for (int u = 0; u < 8; u++) acc[j + u] += (float)v[u];
            }
        }
#pragma unroll
        for (int j = 0; j < 32; j++) sp[ol][part * 32 + j] = acc[j];
    }
    __syncthreads();

    // phase 2: in-place cprelu + mix, coalesced over o
    for (int rr = 0; rr < 32; rr++) {
        const int c = rr * 4 + (t >> 6);   // wave-uniform
        const int o = t & 63;
        const size_t oi = ((size_t)b * 128 + c) * 4096 + o0 + o;
        float v = out[oi];
        const float pw = p3[c];
        float y = (v >= 0.f) ? v : v * pw;
        y = (y - PM) * PIS;
        out[oi] = sp[o][c] * RHALF + y * RHALF;
    }
}

// ---------------------------------------------------------------- launch
extern "C" void kernel_launch(void* const* d_in, const int* in_sizes, int n_in,
                              void* d_out, int out_size, void* d_ws, size_t ws_size,
                              hipStream_t stream) {
    (void)in_sizes; (void)n_in; (void)out_size; (void)ws_size;
    const float* x    = (const float*)d_in[0];
    const float* conn = (const float*)d_in[1];
    const float* w1   = (const float*)d_in[2];
    const float* b1   = (const float*)d_in[3];
    const float* p1   = (const float*)d_in[4];
    const float* w2   = (const float*)d_in[5];
    const float* b2   = (const float*)d_in[6];
    const float* p2   = (const float*)d_in[7];
    const float* wm   = (const float*)d_in[8];
    const float* bm   = (const float*)d_in[9];
    const float* p3   = (const float*)d_in[10];
    const float* wsw  = (const float*)d_in[11];
    const float* bs   = (const float*)d_in[12];
    float* out = (float*)d_out;

    char* ws = (char*)d_ws;
    __bf16* h3  = (__bf16*)(ws);                          // 2048*8192*2 = 33,554,432
    __bf16* s_t = (__bf16*)(ws + 33554432);               // 16*8192*128*2 = 33,554,432
    __bf16* W1p = (__bf16*)(ws + 67108864);               // 96*64*2   = 12,288
    __bf16* W2p = (__bf16*)(ws + 67108864 + 12288);       // 112*96*2  = 21,504
    __bf16* WMp = (__bf16*)(ws + 67108864 + 33792);       // 128*128*2 = 32,768
    __bf16* WSp = (__bf16*)(ws + 67108864 + 66560);       // 128*64*2  = 16,384
    int* idx = (int*)(ws + 67108864 + 82944);             // 4096*16*4 = 262,144
    int* cnt = (int*)(ws + 67108864 + 82944 + 262144);    // 4096*4

    k_prep<<<32, 256, 0, stream>>>(w1, w2, wm, wsw, W1p, W2p, WMp, WSp);
    k_argmax<<<4096, 256, 0, stream>>>(conn, cnt, idx);
    k_chain<<<dim3(8192 / 128, 16), 256, 0, stream>>>(x, b1, p1, b2, p2, bm, bs,
                                                      W1p, W2p, WMp, WSp, h3, s_t);
    k_gemm<<<dim3(4096 / 128, 2048 / 128), 256, 0, stream>>>(h3, conn, out);
    k_combine<<<dim3(4096 / 64, 16), 256, 0, stream>>>(out, s_t, idx, cnt, p3);
}

// Round 2
// 549.294 us; speedup vs baseline: 1.0848x; 1.0848x over previous
//
#include <hip/hip_runtime.h>
#include <hip/hip_bf16.h>
#include <stdint.h>

using bf16x8 = __attribute__((ext_vector_type(8))) __bf16;
using bf16x4 = __attribute__((ext_vector_type(4))) __bf16;
using f32x4  = __attribute__((ext_vector_type(4))) float;

typedef const uint32_t __attribute__((address_space(1)))* gas_ptr;
typedef uint32_t __attribute__((address_space(3)))* las_ptr;

__device__ __forceinline__ void load_lds16(const void* g, void* l) {
    __builtin_amdgcn_global_load_lds((gas_ptr)g, (las_ptr)l, 16, 0, 0);
}

// cprelu post-normalization constants (PRELU_INIT = 0.25)
#define PM  0.29920671030107454f
#define PIS 1.5046096f
#define RHALF 0.70710678118654752f

// ---------------------------------------------------------------- k_prep
__global__ __launch_bounds__(256) void k_prep(const float* __restrict__ w1,
                                              const float* __restrict__ w2,
                                              const float* __restrict__ wm,
                                              const float* __restrict__ wsw,
                                              __bf16* __restrict__ W1p,
                                              __bf16* __restrict__ W2p,
                                              __bf16* __restrict__ WMp,
                                              __bf16* __restrict__ WSp)
{
    const int id = blockIdx.x * 256 + threadIdx.x;
    const int stride = gridDim.x * 256;
    for (int i = id; i < 96 * 64; i += stride) {
        int oc = i >> 6, ic = i & 63;
        W1p[i] = (__bf16)((oc < 83) ? w1[oc * 64 + ic] : 0.f);
    }
    for (int i = id; i < 112 * 96; i += stride) {
        int oc = i / 96, ic = i % 96;
        W2p[i] = (__bf16)((oc < 102 && ic < 83) ? w2[oc * 83 + ic] : 0.f);
    }
    for (int i = id; i < 128 * 128; i += stride) {
        int oc = i >> 7, ic = i & 127;
        WMp[i] = (__bf16)((ic < 102) ? wm[oc * 102 + ic] : 0.f);
    }
    for (int i = id; i < 128 * 64; i += stride) {
        WSp[i] = (__bf16)wsw[i];
    }
}

// ---------------------------------------------------------------- k_conv
// Fused: conn fp32 -> bf16 (row-private, read-all-then-write so in-place is
// safe) + per-row max + tie-index collection (exact fp32 equality, cap 16).
__global__ __launch_bounds__(256) void k_conv(const float* __restrict__ conn,
                                              __bf16* __restrict__ cb,
                                              size_t rowstride,
                                              int* __restrict__ cnt,
                                              int* __restrict__ idx)
{
    const int o = blockIdx.x;
    const int t = threadIdx.x;
    const float* row = conn + (size_t)o * 8192;
    float4 v[8];
    float m = -1e30f;
#pragma unroll
    for (int q = 0; q < 8; q++) {
        v[q] = *(const float4*)(row + (size_t)(q * 256 + t) * 4);
        m = fmaxf(m, fmaxf(fmaxf(v[q].x, v[q].y), fmaxf(v[q].z, v[q].w)));
    }
    __syncthreads();   // all reads drained before in-place overwrite
    __bf16* drow = cb + (size_t)o * rowstride;
#pragma unroll
    for (int q = 0; q < 8; q++) {
        bf16x4 w;
        w[0] = (__bf16)v[q].x; w[1] = (__bf16)v[q].y;
        w[2] = (__bf16)v[q].z; w[3] = (__bf16)v[q].w;
        *(bf16x4*)(drow + (size_t)(q * 256 + t) * 4) = w;
    }
#pragma unroll
    for (int off = 32; off > 0; off >>= 1) m = fmaxf(m, __shfl_down(m, off, 64));
    __shared__ float wmax[4];
    __shared__ int scnt;
    if ((t & 63) == 0) wmax[t >> 6] = m;
    if (t == 0) scnt = 0;
    __syncthreads();
    const float rmax = fmaxf(fmaxf(wmax[0], wmax[1]), fmaxf(wmax[2], wmax[3]));
#pragma unroll
    for (int q = 0; q < 8; q++) {
        float vv[4] = {v[q].x, v[q].y, v[q].z, v[q].w};
#pragma unroll
        for (int e = 0; e < 4; e++) {
            if (vv[e] >= rmax) {
                int p = atomicAdd(&scnt, 1);
                if (p < 16) idx[o * 16 + p] = (q * 256 + t) * 4 + e;
            }
        }
    }
    __syncthreads();
    if (t == 0) cnt[o] = scnt < 16 ? scnt : 16;
}

// ---------------------------------------------------------------- k_chain
template<int KS>
__device__ __forceinline__ f32x4 mfma_tile(const __bf16* __restrict__ W, int wstride, int mt,
                                           const __bf16* B, int bstride, int nt, int lane)
{
    f32x4 acc = {0.f, 0.f, 0.f, 0.f};
    const int l15 = lane & 15;
    const int kg  = (lane >> 4) << 3;
    const __bf16* wp = W + (mt * 16 + l15) * wstride + kg;
    const __bf16* bp = B + (nt * 16 + l15) * bstride + kg;
#pragma unroll
    for (int ks = 0; ks < KS; ks++) {
        bf16x8 av = *(const bf16x8*)(wp + ks * 32);
        bf16x8 bv = *(const bf16x8*)(bp + ks * 32);
        acc = __builtin_amdgcn_mfma_f32_16x16x32_bf16(av, bv, acc, 0, 0, 0);
    }
    return acc;
}

__global__ __launch_bounds__(256) void k_chain(
    const float* __restrict__ x,
    const float* __restrict__ b1, const float* __restrict__ p1,
    const float* __restrict__ b2, const float* __restrict__ p2,
    const float* __restrict__ bm, const float* __restrict__ bs,
    const __bf16* __restrict__ W1p, const __bf16* __restrict__ W2p,
    const __bf16* __restrict__ WMp, const __bf16* __restrict__ WSp,
    __bf16* __restrict__ h3, __bf16* __restrict__ s_t)
{
    __shared__ __bf16 buf0[128 * 136];   // Xt (stride 72) then H2t (stride 136)
    __shared__ __bf16 H1t[128 * 104];
    __shared__ float  bl[672];
    float* b1l = bl;       float* p1l = bl + 96;
    float* b2l = bl + 192; float* p2l = bl + 304;
    float* bml = bl + 416; float* bsl = bl + 544;

    const int t = threadIdx.x, lane = t & 63, wid = t >> 6;
    const int b = blockIdx.y;
    const int p0 = blockIdx.x * 128;

    for (int i = t; i < 96; i += 256)  { b1l[i] = (i < 83)  ? b1[i] : 0.f; p1l[i] = (i < 83)  ? p1[i] : 0.f; }
    for (int i = t; i < 112; i += 256) { b2l[i] = (i < 102) ? b2[i] : 0.f; p2l[i] = (i < 102) ? p2[i] : 0.f; }
    for (int i = t; i < 128; i += 256) { bml[i] = bm[i]; bsl[i] = bs[i]; }

    {
        const int p = t & 127;
        const int chalf = t >> 7;
#pragma unroll 4
        for (int it = 0; it < 32; it++) {
            int c = it * 2 + chalf;
            buf0[p * 72 + c] = (__bf16)x[((size_t)b * 64 + c) * 8192 + p0 + p];
        }
    }
    __syncthreads();

    const int quad4 = (lane >> 4) << 2;
    const int l15 = lane & 15;

    for (int tt = wid; tt < 64; tt += 4) {
        int mt = tt >> 3, nt = tt & 7;
        f32x4 a = mfma_tile<2>(WSp, 64, mt, buf0, 72, nt, lane);
        int ocb = mt * 16 + quad4;
        int pos = nt * 16 + l15;
        bf16x4 ov;
#pragma unroll
        for (int r = 0; r < 4; r++) ov[r] = (__bf16)(a[r] + bsl[ocb + r]);
        *(bf16x4*)(s_t + ((size_t)b * 8192 + p0 + pos) * 128 + ocb) = ov;
    }
    for (int tt = wid; tt < 48; tt += 4) {
        int mt = tt / 8, nt = tt % 8;
        f32x4 a = mfma_tile<2>(W1p, 64, mt, buf0, 72, nt, lane);
        int ocb = mt * 16 + quad4;
        int pos = nt * 16 + l15;
        bf16x4 ov;
#pragma unroll
        for (int r = 0; r < 4; r++) {
            float v = a[r] + b1l[ocb + r];
            v = (v >= 0.f) ? v : v * p1l[ocb + r];
            ov[r] = (__bf16)((v - PM) * PIS);
        }
        *(bf16x4*)(&H1t[pos * 104 + ocb]) = ov;
    }
    __syncthreads();

    for (int tt = wid; tt < 56; tt += 4) {
        int mt = tt / 8, nt = tt % 8;
        f32x4 a = mfma_tile<3>(W2p, 96, mt, H1t, 104, nt, lane);
        int ocb = mt * 16 + quad4;
        int pos = nt * 16 + l15;
        bf16x4 ov;
#pragma unroll
        for (int r = 0; r < 4; r++) {
            float v = a[r] + b2l[ocb + r];
            v = (v >= 0.f) ? v : v * p2l[ocb + r];
            ov[r] = (__bf16)((v - PM) * PIS);
        }
        *(bf16x4*)(&buf0[pos * 136 + ocb]) = ov;
    }
    for (int i = t; i < 128 * 16; i += 256) {
        int pos = i >> 4, c = 112 + (i & 15);
        buf0[pos * 136 + c] = (__bf16)0.f;
    }
    __syncthreads();

    for (int tt = wid; tt < 64; tt += 4) {
        int mt = tt >> 3, nt = tt & 7;
        f32x4 a = mfma_tile<4>(WMp, 128, mt, buf0, 136, nt, lane);
        int ocb = mt * 16 + quad4;
        int pos = nt * 16 + l15;
#pragma unroll
        for (int r = 0; r < 4; r++)
            h3[((size_t)b * 128 + ocb + r) * 8192 + p0 + pos] = (__bf16)(a[r] + bml[ocb + r]);
    }
}

// ---------------------------------------------------------------- k_gemm
// C[2048,4096] = A[2048,8192](bf16) x B[4096,Kstride](bf16, row-major N x K)
// Pure bf16, both operands via global_load_lds width-16, XOR bank swizzle:
// LDS 16B-chunk (row, kg) stored at chunk index row*4 + (kg ^ ((row>>1)&3)).
__global__ __launch_bounds__(256) void k_gemm(const __bf16* __restrict__ A,
                                              const __bf16* __restrict__ B,
                                              size_t bstride,
                                              float* __restrict__ C)
{
    __shared__ __bf16 la[128 * 32];
    __shared__ __bf16 lb[128 * 32];
    const int t = threadIdx.x;
    const int lane = t & 63;
    const int wid = t >> 6;
    const int tM = blockIdx.y * 128;
    const int tN = blockIdx.x * 128;
    const int wm2 = (wid & 1) * 64;
    const int wn2 = (wid >> 1) * 64;

    f32x4 acc[4][4];
    const f32x4 zero = {0.f, 0.f, 0.f, 0.f};
#pragma unroll
    for (int i = 0; i < 4; i++)
#pragma unroll
        for (int j = 0; j < 4; j++) acc[i][j] = zero;

    const __bf16* Ab = A + (size_t)tM * 8192;
    const __bf16* Bb = B + (size_t)tN * bstride;
    const int ar = t >> 2;                          // tile row (issue 0)
    const int ak = ((t & 3) ^ ((t >> 3) & 3)) * 8;  // swizzled global k-chunk
    const int l15 = lane & 15;
    const int q = lane >> 4;

    // constant LDS read offsets (bf16 elems), swizzle-aware
    int aoff[4], boff[4];
#pragma unroll
    for (int i = 0; i < 4; i++) {
        int row = wm2 + i * 16 + l15;
        aoff[i] = row * 32 + ((q ^ ((row >> 1) & 3)) * 8);
    }
#pragma unroll
    for (int j = 0; j < 4; j++) {
        int row = wn2 + j * 16 + l15;
        boff[j] = row * 32 + ((q ^ ((row >> 1) & 3)) * 8);
    }

    for (int kt = 0; kt < 8192; kt += 32) {
        load_lds16(Ab + (size_t)ar * 8192 + kt + ak, la + t * 8);
        load_lds16(Ab + (size_t)(64 + ar) * 8192 + kt + ak, la + 2048 + t * 8);
        load_lds16(Bb + (size_t)ar * bstride + kt + ak, lb + t * 8);
        load_lds16(Bb + (size_t)(64 + ar) * bstride + kt + ak, lb + 2048 + t * 8);
        __syncthreads();
        bf16x8 af[4], bfr[4];
#pragma unroll
        for (int i = 0; i < 4; i++) af[i]  = *(const bf16x8*)(la + aoff[i]);
#pragma unroll
        for (int j = 0; j < 4; j++) bfr[j] = *(const bf16x8*)(lb + boff[j]);
#pragma unroll
        for (int i = 0; i < 4; i++)
#pragma unroll
            for (int j = 0; j < 4; j++)
                acc[i][j] = __builtin_amdgcn_mfma_f32_16x16x32_bf16(af[i], bfr[j], acc[i][j], 0, 0, 0);
        __syncthreads();
    }

    const int quad4 = (lane >> 4) * 4;
#pragma unroll
    for (int i = 0; i < 4; i++) {
        int gm = tM + wm2 + i * 16 + quad4;
#pragma unroll
        for (int j = 0; j < 4; j++) {
            int gn = tN + wn2 + j * 16 + l15;
#pragma unroll
            for (int r = 0; r < 4; r++)
                C[(size_t)(gm + r) * 4096 + gn] = acc[i][j][r];
        }
    }
}

// ---------------------------------------------------------------- k_combine
__global__ __launch_bounds__(256) void k_combine(float* __restrict__ out,
                                                 const __bf16* __restrict__ s_t,
                                                 const int* __restrict__ idx,
                                                 const int* __restrict__ cnt,
                                                 const float* __restrict__ p3)
{
    __shared__ float sp[64][133];
    const int b = blockIdx.y;
    const int o0 = blockIdx.x * 64;
    const int t = threadIdx.x;

    {
        const int ol = t >> 2;
        const int part = t & 3;
        const int o = o0 + ol;
        const int n = cnt[o];
        float acc[32];
#pragma unroll
        for (int j = 0; j < 32; j++) acc[j] = 0.f;
        for (int k = 0; k < n; k++) {
            const int i = idx[o * 16 + k];
            const __bf16* row = s_t + ((size_t)b * 8192 + i) * 128 + part * 32;
#pragma unroll
            for (int j = 0; j < 32; j += 8) {
                bf16x8 v = *(const bf16x8*)(row + j);
#pragma unroll
                for (int u = 0; u < 8; u++) acc[j + u] += (float)v[u];
            }
        }
#pragma unroll
        for (int j = 0; j < 32; j++) sp[ol][part * 32 + j] = acc[j];
    }
    __syncthreads();

    for (int rr = 0; rr < 32; rr++) {
        const int c = rr * 4 + (t >> 6);
        const int o = t & 63;
        const size_t oi = ((size_t)b * 128 + c) * 4096 + o0 + o;
        float v = out[oi];
        const float pw = p3[c];
        float y = (v >= 0.f) ? v : v * pw;
        y = (y - PM) * PIS;
        out[oi] = sp[o][c] * RHALF + y * RHALF;
    }
}

// ---------------------------------------------------------------- launch
extern "C" void kernel_launch(void* const* d_in, const int* in_sizes, int n_in,
                              void* d_out, int out_size, void* d_ws, size_t ws_size,
                              hipStream_t stream) {
    (void)in_sizes; (void)n_in; (void)out_size;
    const float* x    = (const float*)d_in[0];
    const float* conn = (const float*)d_in[1];
    const float* w1   = (const float*)d_in[2];
    const float* b1   = (const float*)d_in[3];
    const float* p1   = (const float*)d_in[4];
    const float* w2   = (const float*)d_in[5];
    const float* b2   = (const float*)d_in[6];
    const float* p2   = (const float*)d_in[7];
    const float* wm   = (const float*)d_in[8];
    const float* bm   = (const float*)d_in[9];
    const float* p3   = (const float*)d_in[10];
    const float* wsw  = (const float*)d_in[11];
    const float* bs   = (const float*)d_in[12];
    float* out = (float*)d_out;

    char* ws = (char*)d_ws;
    __bf16* h3  = (__bf16*)(ws);                          // 33,554,432 B
    __bf16* s_t = (__bf16*)(ws + 33554432);               // 33,554,432 B
    __bf16* W1p = (__bf16*)(ws + 67108864);               // 12,288
    __bf16* W2p = (__bf16*)(ws + 67108864 + 12288);       // 21,504
    __bf16* WMp = (__bf16*)(ws + 67108864 + 33792);       // 32,768
    __bf16* WSp = (__bf16*)(ws + 67108864 + 66560);       // 16,384
    int* idx = (int*)(ws + 67108864 + 82944);             // 262,144
    int* cnt = (int*)(ws + 67108864 + 82944 + 262144);    // 16,384

    // conn bf16 destination: workspace if it fits, else in-place over the
    // fp32 conn buffer (harness restores inputs before every launch; each
    // k_conv block reads its whole row into registers before overwriting).
    const size_t connb_off = 67108864 + 82944 + 262144 + 16384;
    __bf16* connb;
    size_t  cstride;
    if (ws_size >= connb_off + (size_t)4096 * 8192 * 2) {
        connb = (__bf16*)(ws + connb_off);
        cstride = 8192;
    } else {
        connb = (__bf16*)const_cast<float*>(conn);
        cstride = 16384;   // bf16 row packed into first half of its fp32 row
    }

    k_prep<<<32, 256, 0, stream>>>(w1, w2, wm, wsw, W1p, W2p, WMp, WSp);
    k_conv<<<4096, 256, 0, stream>>>(conn, connb, cstride, cnt, idx);
    k_chain<<<dim3(8192 / 128, 16), 256, 0, stream>>>(x, b1, p1, b2, p2, bm, bs,
                                                      W1p, W2p, WMp, WSp, h3, s_t);
    k_gemm<<<dim3(4096 / 128, 2048 / 128), 256, 0, stream>>>(h3, connb, cstride, out);
    k_combine<<<dim3(4096 / 64, 16), 256, 0, stream>>>(out, s_t, idx, cnt, p3);
}

// Round 3
// 523.447 us; speedup vs baseline: 1.1383x; 1.0494x over previous
//
#include <hip/hip_runtime.h>
#include <hip/hip_bf16.h>
#include <stdint.h>

using bf16x8 = __attribute__((ext_vector_type(8))) __bf16;
using bf16x4 = __attribute__((ext_vector_type(4))) __bf16;
using f32x4  = __attribute__((ext_vector_type(4))) float;

typedef const uint32_t __attribute__((address_space(1)))* gas_ptr;
typedef uint32_t __attribute__((address_space(3)))* las_ptr;

__device__ __forceinline__ void load_lds16(const void* g, void* l) {
    __builtin_amdgcn_global_load_lds((gas_ptr)g, (las_ptr)l, 16, 0, 0);
}

// cprelu post-normalization constants (PRELU_INIT = 0.25)
#define PM  0.29920671030107454f
#define PIS 1.5046096f
#define RHALF 0.70710678118654752f

// ---------------------------------------------------------------- k_prep
__global__ __launch_bounds__(256) void k_prep(const float* __restrict__ w1,
                                              const float* __restrict__ w2,
                                              const float* __restrict__ wm,
                                              const float* __restrict__ wsw,
                                              __bf16* __restrict__ W1p,
                                              __bf16* __restrict__ W2p,
                                              __bf16* __restrict__ WMp,
                                              __bf16* __restrict__ WSp)
{
    const int id = blockIdx.x * 256 + threadIdx.x;
    const int stride = gridDim.x * 256;
    for (int i = id; i < 96 * 64; i += stride) {
        int oc = i >> 6, ic = i & 63;
        W1p[i] = (__bf16)((oc < 83) ? w1[oc * 64 + ic] : 0.f);
    }
    for (int i = id; i < 112 * 96; i += stride) {
        int oc = i / 96, ic = i % 96;
        W2p[i] = (__bf16)((oc < 102 && ic < 83) ? w2[oc * 83 + ic] : 0.f);
    }
    for (int i = id; i < 128 * 128; i += stride) {
        int oc = i >> 7, ic = i & 127;
        WMp[i] = (__bf16)((ic < 102) ? wm[oc * 102 + ic] : 0.f);
    }
    for (int i = id; i < 128 * 64; i += stride) {
        WSp[i] = (__bf16)wsw[i];
    }
}

// ---------------------------------------------------------------- k_conv
// Fused: conn fp32 -> bf16 (row-private, read-all-then-write so in-place is
// safe) + per-row max + tie-index collection (exact fp32 equality, cap 16).
__global__ __launch_bounds__(256) void k_conv(const float* __restrict__ conn,
                                              __bf16* __restrict__ cb,
                                              size_t rowstride,
                                              int* __restrict__ cnt,
                                              int* __restrict__ idx)
{
    const int o = blockIdx.x;
    const int t = threadIdx.x;
    const float* row = conn + (size_t)o * 8192;
    float4 v[8];
    float m = -1e30f;
#pragma unroll
    for (int q = 0; q < 8; q++) {
        v[q] = *(const float4*)(row + (size_t)(q * 256 + t) * 4);
        m = fmaxf(m, fmaxf(fmaxf(v[q].x, v[q].y), fmaxf(v[q].z, v[q].w)));
    }
    __syncthreads();   // all reads drained before in-place overwrite
    __bf16* drow = cb + (size_t)o * rowstride;
#pragma unroll
    for (int q = 0; q < 8; q++) {
        bf16x4 w;
        w[0] = (__bf16)v[q].x; w[1] = (__bf16)v[q].y;
        w[2] = (__bf16)v[q].z; w[3] = (__bf16)v[q].w;
        *(bf16x4*)(drow + (size_t)(q * 256 + t) * 4) = w;
    }
#pragma unroll
    for (int off = 32; off > 0; off >>= 1) m = fmaxf(m, __shfl_down(m, off, 64));
    __shared__ float wmax[4];
    __shared__ int scnt;
    if ((t & 63) == 0) wmax[t >> 6] = m;
    if (t == 0) scnt = 0;
    __syncthreads();
    const float rmax = fmaxf(fmaxf(wmax[0], wmax[1]), fmaxf(wmax[2], wmax[3]));
#pragma unroll
    for (int q = 0; q < 8; q++) {
        float vv[4] = {v[q].x, v[q].y, v[q].z, v[q].w};
#pragma unroll
        for (int e = 0; e < 4; e++) {
            if (vv[e] >= rmax) {
                int p = atomicAdd(&scnt, 1);
                if (p < 16) idx[o * 16 + p] = (q * 256 + t) * 4 + e;
            }
        }
    }
    __syncthreads();
    if (t == 0) cnt[o] = scnt < 16 ? scnt : 16;
}

// ---------------------------------------------------------------- k_chain
// pos-tile = 64 -> LDS 33.4 KB -> 4 blocks/CU, 2048 blocks.
template<int KS>
__device__ __forceinline__ f32x4 mfma_tile(const __bf16* __restrict__ W, int wstride, int mt,
                                           const __bf16* B, int bstride, int nt, int lane)
{
    f32x4 acc = {0.f, 0.f, 0.f, 0.f};
    const int l15 = lane & 15;
    const int kg  = (lane >> 4) << 3;
    const __bf16* wp = W + (mt * 16 + l15) * wstride + kg;
    const __bf16* bp = B + (nt * 16 + l15) * bstride + kg;
#pragma unroll
    for (int ks = 0; ks < KS; ks++) {
        bf16x8 av = *(const bf16x8*)(wp + ks * 32);
        bf16x8 bv = *(const bf16x8*)(bp + ks * 32);
        acc = __builtin_amdgcn_mfma_f32_16x16x32_bf16(av, bv, acc, 0, 0, 0);
    }
    return acc;
}

__global__ __launch_bounds__(256) void k_chain(
    const float* __restrict__ x,
    const float* __restrict__ b1, const float* __restrict__ p1,
    const float* __restrict__ b2, const float* __restrict__ p2,
    const float* __restrict__ bm, const float* __restrict__ bs,
    const __bf16* __restrict__ W1p, const __bf16* __restrict__ W2p,
    const __bf16* __restrict__ WMp, const __bf16* __restrict__ WSp,
    __bf16* __restrict__ h3, __bf16* __restrict__ s_t)
{
    __shared__ __bf16 buf0[64 * 136];   // Xt (stride 72) then H2t (stride 136)
    __shared__ __bf16 H1t[64 * 104];
    __shared__ float  bl[672];
    float* b1l = bl;       float* p1l = bl + 96;
    float* b2l = bl + 192; float* p2l = bl + 304;
    float* bml = bl + 416; float* bsl = bl + 544;

    const int t = threadIdx.x, lane = t & 63, wid = t >> 6;
    const int b = blockIdx.y;
    const int p0 = blockIdx.x * 64;

    for (int i = t; i < 96; i += 256)  { b1l[i] = (i < 83)  ? b1[i] : 0.f; p1l[i] = (i < 83)  ? p1[i] : 0.f; }
    for (int i = t; i < 112; i += 256) { b2l[i] = (i < 102) ? b2[i] : 0.f; p2l[i] = (i < 102) ? p2[i] : 0.f; }
    for (int i = t; i < 128; i += 256) { bml[i] = bm[i]; bsl[i] = bs[i]; }

    {
        const int p = t & 63;
        const int cg = t >> 6;     // 0..3
#pragma unroll 4
        for (int it = 0; it < 16; it++) {
            int c = it * 4 + cg;
            buf0[p * 72 + c] = (__bf16)x[((size_t)b * 64 + c) * 8192 + p0 + p];
        }
    }
    __syncthreads();

    const int quad4 = (lane >> 4) << 2;
    const int l15 = lane & 15;

    // shortcut S = WS*X + bs  (8 mt x 4 nt)
    for (int tt = wid; tt < 32; tt += 4) {
        int mt = tt >> 2, nt = tt & 3;
        f32x4 a = mfma_tile<2>(WSp, 64, mt, buf0, 72, nt, lane);
        int ocb = mt * 16 + quad4;
        int pos = nt * 16 + l15;
        bf16x4 ov;
#pragma unroll
        for (int r = 0; r < 4; r++) ov[r] = (__bf16)(a[r] + bsl[ocb + r]);
        *(bf16x4*)(s_t + ((size_t)b * 8192 + p0 + pos) * 128 + ocb) = ov;
    }
    // H1 = cprelu(W1*X + b1)  (6 mt x 4 nt)
    for (int tt = wid; tt < 24; tt += 4) {
        int mt = tt >> 2, nt = tt & 3;
        f32x4 a = mfma_tile<2>(W1p, 64, mt, buf0, 72, nt, lane);
        int ocb = mt * 16 + quad4;
        int pos = nt * 16 + l15;
        bf16x4 ov;
#pragma unroll
        for (int r = 0; r < 4; r++) {
            float v = a[r] + b1l[ocb + r];
            v = (v >= 0.f) ? v : v * p1l[ocb + r];
            ov[r] = (__bf16)((v - PM) * PIS);
        }
        *(bf16x4*)(&H1t[pos * 104 + ocb]) = ov;
    }
    __syncthreads();

    // H2 = cprelu(W2*H1 + b2)  (7 mt x 4 nt), into buf0 (Xt dead)
    for (int tt = wid; tt < 28; tt += 4) {
        int mt = tt >> 2, nt = tt & 3;
        f32x4 a = mfma_tile<3>(W2p, 96, mt, H1t, 104, nt, lane);
        int ocb = mt * 16 + quad4;
        int pos = nt * 16 + l15;
        bf16x4 ov;
#pragma unroll
        for (int r = 0; r < 4; r++) {
            float v = a[r] + b2l[ocb + r];
            v = (v >= 0.f) ? v : v * p2l[ocb + r];
            ov[r] = (__bf16)((v - PM) * PIS);
        }
        *(bf16x4*)(&buf0[pos * 136 + ocb]) = ov;
    }
    // zero H2 pad channels 112..127
    for (int i = t; i < 64 * 16; i += 256) {
        int pos = i >> 4, c = 112 + (i & 15);
        buf0[pos * 136 + c] = (__bf16)0.f;
    }
    __syncthreads();

    // H3 = WM*H2 + bm  (8 mt x 4 nt)
    for (int tt = wid; tt < 32; tt += 4) {
        int mt = tt >> 2, nt = tt & 3;
        f32x4 a = mfma_tile<4>(WMp, 128, mt, buf0, 136, nt, lane);
        int ocb = mt * 16 + quad4;
        int pos = nt * 16 + l15;
#pragma unroll
        for (int r = 0; r < 4; r++)
            h3[((size_t)b * 128 + ocb + r) * 8192 + p0 + pos] = (__bf16)(a[r] + bml[ocb + r]);
    }
}

// ---------------------------------------------------------------- k_gemm
// C[2048,4096] = A[2048,8192](bf16) x B[4096,bstride](bf16, N x K rows)
// 128x128 tile, BK=32, split-K via blockIdx.z: z writes C0 (=d_out) or C1.
__global__ __launch_bounds__(256) void k_gemm(const __bf16* __restrict__ A,
                                              const __bf16* __restrict__ B,
                                              size_t bstride,
                                              float* __restrict__ C0,
                                              float* __restrict__ C1,
                                              int KH)
{
    __shared__ __bf16 la[128 * 32];
    __shared__ __bf16 lb[128 * 32];
    const int t = threadIdx.x;
    const int lane = t & 63;
    const int wid = t >> 6;
    const int tM = blockIdx.y * 128;
    const int tN = blockIdx.x * 128;
    const int kz = blockIdx.z;
    const int k0 = kz * KH;
    float* __restrict__ C = kz ? C1 : C0;
    const int wm2 = (wid & 1) * 64;
    const int wn2 = (wid >> 1) * 64;

    f32x4 acc[4][4];
    const f32x4 zero = {0.f, 0.f, 0.f, 0.f};
#pragma unroll
    for (int i = 0; i < 4; i++)
#pragma unroll
        for (int j = 0; j < 4; j++) acc[i][j] = zero;

    const __bf16* Ab = A + (size_t)tM * 8192;
    const __bf16* Bb = B + (size_t)tN * bstride;
    const int ar = t >> 2;                          // tile row (issue 0)
    const int ak = ((t & 3) ^ ((t >> 3) & 3)) * 8;  // swizzled global k-chunk
    const int l15 = lane & 15;
    const int q = lane >> 4;

    int aoff[4], boff[4];
#pragma unroll
    for (int i = 0; i < 4; i++) {
        int row = wm2 + i * 16 + l15;
        aoff[i] = row * 32 + ((q ^ ((row >> 1) & 3)) * 8);
    }
#pragma unroll
    for (int j = 0; j < 4; j++) {
        int row = wn2 + j * 16 + l15;
        boff[j] = row * 32 + ((q ^ ((row >> 1) & 3)) * 8);
    }

    for (int kt = k0; kt < k0 + KH; kt += 32) {
        load_lds16(Ab + (size_t)ar * 8192 + kt + ak, la + t * 8);
        load_lds16(Ab + (size_t)(64 + ar) * 8192 + kt + ak, la + 2048 + t * 8);
        load_lds16(Bb + (size_t)ar * bstride + kt + ak, lb + t * 8);
        load_lds16(Bb + (size_t)(64 + ar) * bstride + kt + ak, lb + 2048 + t * 8);
        __syncthreads();
        bf16x8 af[4], bfr[4];
#pragma unroll
        for (int i = 0; i < 4; i++) af[i]  = *(const bf16x8*)(la + aoff[i]);
#pragma unroll
        for (int j = 0; j < 4; j++) bfr[j] = *(const bf16x8*)(lb + boff[j]);
#pragma unroll
        for (int i = 0; i < 4; i++)
#pragma unroll
            for (int j = 0; j < 4; j++)
                acc[i][j] = __builtin_amdgcn_mfma_f32_16x16x32_bf16(af[i], bfr[j], acc[i][j], 0, 0, 0);
        __syncthreads();
    }

    const int quad4 = (lane >> 4) * 4;
#pragma unroll
    for (int i = 0; i < 4; i++) {
        int gm = tM + wm2 + i * 16 + quad4;
#pragma unroll
        for (int j = 0; j < 4; j++) {
            int gn = tN + wn2 + j * 16 + l15;
#pragma unroll
            for (int r = 0; r < 4; r++)
                C[(size_t)(gm + r) * 4096 + gn] = acc[i][j][r];
        }
    }
}

// ---------------------------------------------------------------- k_combine
// out = RHALF*pooled_shortcut + RHALF*cprelu(P0 (+P1), p3); P0 lives in out.
__global__ __launch_bounds__(256) void k_combine(float* __restrict__ out,
                                                 const float* __restrict__ P1,
                                                 int nsplit,
                                                 const __bf16* __restrict__ s_t,
                                                 const int* __restrict__ idx,
                                                 const int* __restrict__ cnt,
                                                 const float* __restrict__ p3)
{
    __shared__ float sp[64][133];
    const int b = blockIdx.y;
    const int o0 = blockIdx.x * 64;
    const int t = threadIdx.x;

    {
        const int ol = t >> 2;
        const int part = t & 3;
        const int o = o0 + ol;
        const int n = cnt[o];
        float acc[32];
#pragma unroll
        for (int j = 0; j < 32; j++) acc[j] = 0.f;
        for (int k = 0; k < n; k++) {
            const int i = idx[o * 16 + k];
            const __bf16* row = s_t + ((size_t)b * 8192 + i) * 128 + part * 32;
#pragma unroll
            for (int j = 0; j < 32; j += 8) {
                bf16x8 v = *(const bf16x8*)(row + j);
#pragma unroll
                for (int u = 0; u < 8; u++) acc[j + u] += (float)v[u];
            }
        }
#pragma unroll
        for (int j = 0; j < 32; j++) sp[ol][part * 32 + j] = acc[j];
    }
    __syncthreads();

    if (nsplit == 2) {
        for (int rr = 0; rr < 32; rr++) {
            const int c = rr * 4 + (t >> 6);
            const int o = t & 63;
            const size_t oi = ((size_t)b * 128 + c) * 4096 + o0 + o;
            float v = out[oi] + P1[oi];
            const float pw = p3[c];
            float y = (v >= 0.f) ? v : v * pw;
            y = (y - PM) * PIS;
            out[oi] = sp[o][c] * RHALF + y * RHALF;
        }
    } else {
        for (int rr = 0; rr < 32; rr++) {
            const int c = rr * 4 + (t >> 6);
            const int o = t & 63;
            const size_t oi = ((size_t)b * 128 + c) * 4096 + o0 + o;
            float v = out[oi];
            const float pw = p3[c];
            float y = (v >= 0.f) ? v : v * pw;
            y = (y - PM) * PIS;
            out[oi] = sp[o][c] * RHALF + y * RHALF;
        }
    }
}

// ---------------------------------------------------------------- launch
extern "C" void kernel_launch(void* const* d_in, const int* in_sizes, int n_in,
                              void* d_out, int out_size, void* d_ws, size_t ws_size,
                              hipStream_t stream) {
    (void)in_sizes; (void)n_in; (void)out_size;
    const float* x    = (const float*)d_in[0];
    const float* conn = (const float*)d_in[1];
    const float* w1   = (const float*)d_in[2];
    const float* b1   = (const float*)d_in[3];
    const float* p1   = (const float*)d_in[4];
    const float* w2   = (const float*)d_in[5];
    const float* b2   = (const float*)d_in[6];
    const float* p2   = (const float*)d_in[7];
    const float* wm   = (const float*)d_in[8];
    const float* bm   = (const float*)d_in[9];
    const float* p3   = (const float*)d_in[10];
    const float* wsw  = (const float*)d_in[11];
    const float* bs   = (const float*)d_in[12];
    float* out = (float*)d_out;

    char* ws = (char*)d_ws;
    __bf16* h3  = (__bf16*)(ws);                          // 33,554,432 B
    __bf16* s_t = (__bf16*)(ws + 33554432);               // 33,554,432 B
    __bf16* W1p = (__bf16*)(ws + 67108864);               // 12,288
    __bf16* W2p = (__bf16*)(ws + 67108864 + 12288);       // 21,504
    __bf16* WMp = (__bf16*)(ws + 67108864 + 33792);       // 32,768
    __bf16* WSp = (__bf16*)(ws + 67108864 + 66560);       // 16,384
    int* idx = (int*)(ws + 67108864 + 82944);             // 262,144
    int* cnt = (int*)(ws + 67108864 + 82944 + 262144);    // 16,384
    const size_t p1_off    = 67108864 + 82944 + 262144 + 16384;   // 67,470,336
    float* Pk1 = (float*)(ws + p1_off);                   // 33,554,432
    const size_t connb_off = p1_off + 33554432;           // 101,024,768

    // conn bf16 destination: workspace if it fits, else in-place over the
    // fp32 conn input (harness restores inputs before every launch; each
    // k_conv block reads its whole row into registers before overwriting).
    __bf16* connb;
    size_t  cstride;
    if (ws_size >= connb_off + (size_t)4096 * 8192 * 2) {
        connb = (__bf16*)(ws + connb_off);
        cstride = 8192;
    } else {
        connb = (__bf16*)const_cast<float*>(conn);
        cstride = 16384;   // bf16 row packed into first half of its fp32 row
    }
    // split-K only if ws can hold the second partial
    const int nsplit = (ws_size >= p1_off + 33554432) ? 2 : 1;
    const int KH = 8192 / nsplit;

    k_prep<<<32, 256, 0, stream>>>(w1, w2, wm, wsw, W1p, W2p, WMp, WSp);
    k_conv<<<4096, 256, 0, stream>>>(conn, connb, cstride, cnt, idx);
    k_chain<<<dim3(8192 / 64, 16), 256, 0, stream>>>(x, b1, p1, b2, p2, bm, bs,
                                                     W1p, W2p, WMp, WSp, h3, s_t);
    k_gemm<<<dim3(4096 / 128, 2048 / 128, nsplit), 256, 0, stream>>>(h3, connb, cstride,
                                                                     out, Pk1, KH);
    k_combine<<<dim3(4096 / 64, 16), 256, 0, stream>>>(out, Pk1, nsplit, s_t, idx, cnt, p3);
}

// Round 4
// 485.831 us; speedup vs baseline: 1.2265x; 1.0774x over previous
//
#include <hip/hip_runtime.h>
#include <hip/hip_bf16.h>
#include <stdint.h>

using bf16x8 = __attribute__((ext_vector_type(8))) __bf16;
using bf16x4 = __attribute__((ext_vector_type(4))) __bf16;
using f32x4  = __attribute__((ext_vector_type(4))) float;

typedef const uint32_t __attribute__((address_space(1)))* gas_ptr;
typedef uint32_t __attribute__((address_space(3)))* las_ptr;

__device__ __forceinline__ void load_lds16(const void* g, void* l) {
    __builtin_amdgcn_global_load_lds((gas_ptr)g, (las_ptr)l, 16, 0, 0);
}

// cprelu post-normalization constants (PRELU_INIT = 0.25)
#define PM  0.29920671030107454f
#define PIS 1.5046096f
#define RHALF 0.70710678118654752f

// ---------------------------------------------------------------- k_prep
__global__ __launch_bounds__(256) void k_prep(const float* __restrict__ w1,
                                              const float* __restrict__ w2,
                                              const float* __restrict__ wm,
                                              const float* __restrict__ wsw,
                                              __bf16* __restrict__ W1p,
                                              __bf16* __restrict__ W2p,
                                              __bf16* __restrict__ WMp,
                                              __bf16* __restrict__ WSp)
{
    const int id = blockIdx.x * 256 + threadIdx.x;
    const int stride = gridDim.x * 256;
    for (int i = id; i < 96 * 64; i += stride) {
        int oc = i >> 6, ic = i & 63;
        W1p[i] = (__bf16)((oc < 83) ? w1[oc * 64 + ic] : 0.f);
    }
    for (int i = id; i < 112 * 96; i += stride) {
        int oc = i / 96, ic = i % 96;
        W2p[i] = (__bf16)((oc < 102 && ic < 83) ? w2[oc * 83 + ic] : 0.f);
    }
    for (int i = id; i < 128 * 128; i += stride) {
        int oc = i >> 7, ic = i & 127;
        WMp[i] = (__bf16)((ic < 102) ? wm[oc * 102 + ic] : 0.f);
    }
    for (int i = id; i < 128 * 64; i += stride) {
        WSp[i] = (__bf16)wsw[i];
    }
}

// ---------------------------------------------------------------- k_conv
// Fused: conn fp32 -> bf16 (row-private, read-all-then-write so in-place is
// safe) + per-row max + tie-index collection (exact fp32 equality, cap 16).
__global__ __launch_bounds__(256) void k_conv(const float* __restrict__ conn,
                                              __bf16* __restrict__ cb,
                                              size_t rowstride,
                                              int* __restrict__ cnt,
                                              int* __restrict__ idx)
{
    const int o = blockIdx.x;
    const int t = threadIdx.x;
    const float* row = conn + (size_t)o * 8192;
    float4 v[8];
    float m = -1e30f;
#pragma unroll
    for (int q = 0; q < 8; q++) {
        v[q] = *(const float4*)(row + (size_t)(q * 256 + t) * 4);
        m = fmaxf(m, fmaxf(fmaxf(v[q].x, v[q].y), fmaxf(v[q].z, v[q].w)));
    }
    __syncthreads();   // all reads drained before in-place overwrite
    __bf16* drow = cb + (size_t)o * rowstride;
#pragma unroll
    for (int q = 0; q < 8; q++) {
        bf16x4 w;
        w[0] = (__bf16)v[q].x; w[1] = (__bf16)v[q].y;
        w[2] = (__bf16)v[q].z; w[3] = (__bf16)v[q].w;
        *(bf16x4*)(drow + (size_t)(q * 256 + t) * 4) = w;
    }
#pragma unroll
    for (int off = 32; off > 0; off >>= 1) m = fmaxf(m, __shfl_down(m, off, 64));
    __shared__ float wmax[4];
    __shared__ int scnt;
    if ((t & 63) == 0) wmax[t >> 6] = m;
    if (t == 0) scnt = 0;
    __syncthreads();
    const float rmax = fmaxf(fmaxf(wmax[0], wmax[1]), fmaxf(wmax[2], wmax[3]));
#pragma unroll
    for (int q = 0; q < 8; q++) {
        float vv[4] = {v[q].x, v[q].y, v[q].z, v[q].w};
#pragma unroll
        for (int e = 0; e < 4; e++) {
            if (vv[e] >= rmax) {
                int p = atomicAdd(&scnt, 1);
                if (p < 16) idx[o * 16 + p] = (q * 256 + t) * 4 + e;
            }
        }
    }
    __syncthreads();
    if (t == 0) cnt[o] = scnt < 16 ? scnt : 16;
}

// ---------------------------------------------------------------- k_chain
template<int KS>
__device__ __forceinline__ f32x4 mfma_tile(const __bf16* __restrict__ W, int wstride, int mt,
                                           const __bf16* B, int bstride, int nt, int lane)
{
    f32x4 acc = {0.f, 0.f, 0.f, 0.f};
    const int l15 = lane & 15;
    const int kg  = (lane >> 4) << 3;
    const __bf16* wp = W + (mt * 16 + l15) * wstride + kg;
    const __bf16* bp = B + (nt * 16 + l15) * bstride + kg;
#pragma unroll
    for (int ks = 0; ks < KS; ks++) {
        bf16x8 av = *(const bf16x8*)(wp + ks * 32);
        bf16x8 bv = *(const bf16x8*)(bp + ks * 32);
        acc = __builtin_amdgcn_mfma_f32_16x16x32_bf16(av, bv, acc, 0, 0, 0);
    }
    return acc;
}

__global__ __launch_bounds__(256) void k_chain(
    const float* __restrict__ x,
    const float* __restrict__ b1, const float* __restrict__ p1,
    const float* __restrict__ b2, const float* __restrict__ p2,
    const float* __restrict__ bm, const float* __restrict__ bs,
    const __bf16* __restrict__ W1p, const __bf16* __restrict__ W2p,
    const __bf16* __restrict__ WMp, const __bf16* __restrict__ WSp,
    __bf16* __restrict__ h3, __bf16* __restrict__ s_t)
{
    __shared__ __bf16 buf0[64 * 136];   // Xt (stride 72) then H2t (stride 136)
    __shared__ __bf16 un[128 * 72];     // H1t (stride 104) then OutT (stride 72)
    __shared__ float  bl[672];
    __bf16* H1t  = un;                  // 64 x 104 fits in 128*72
    __bf16* OutT = un;                  // 128 x 72
    float* b1l = bl;       float* p1l = bl + 96;
    float* b2l = bl + 192; float* p2l = bl + 304;
    float* bml = bl + 416; float* bsl = bl + 544;

    const int t = threadIdx.x, lane = t & 63, wid = t >> 6;
    const int b = blockIdx.y;
    const int p0 = blockIdx.x * 64;

    for (int i = t; i < 96; i += 256)  { b1l[i] = (i < 83)  ? b1[i] : 0.f; p1l[i] = (i < 83)  ? p1[i] : 0.f; }
    for (int i = t; i < 112; i += 256) { b2l[i] = (i < 102) ? b2[i] : 0.f; p2l[i] = (i < 102) ? p2[i] : 0.f; }
    for (int i = t; i < 128; i += 256) { bml[i] = bm[i]; bsl[i] = bs[i]; }

    {
        const int p = t & 63;
        const int cg = t >> 6;     // 0..3
#pragma unroll 4
        for (int it = 0; it < 16; it++) {
            int c = it * 4 + cg;
            buf0[p * 72 + c] = (__bf16)x[((size_t)b * 64 + c) * 8192 + p0 + p];
        }
    }
    __syncthreads();

    const int quad4 = (lane >> 4) << 2;
    const int l15 = lane & 15;

    // shortcut S = WS*X + bs  (8 mt x 4 nt)
    for (int tt = wid; tt < 32; tt += 4) {
        int mt = tt >> 2, nt = tt & 3;
        f32x4 a = mfma_tile<2>(WSp, 64, mt, buf0, 72, nt, lane);
        int ocb = mt * 16 + quad4;
        int pos = nt * 16 + l15;
        bf16x4 ov;
#pragma unroll
        for (int r = 0; r < 4; r++) ov[r] = (__bf16)(a[r] + bsl[ocb + r]);
        *(bf16x4*)(s_t + ((size_t)b * 8192 + p0 + pos) * 128 + ocb) = ov;
    }
    // H1 = cprelu(W1*X + b1)  (6 mt x 4 nt)
    for (int tt = wid; tt < 24; tt += 4) {
        int mt = tt >> 2, nt = tt & 3;
        f32x4 a = mfma_tile<2>(W1p, 64, mt, buf0, 72, nt, lane);
        int ocb = mt * 16 + quad4;
        int pos = nt * 16 + l15;
        bf16x4 ov;
#pragma unroll
        for (int r = 0; r < 4; r++) {
            float v = a[r] + b1l[ocb + r];
            v = (v >= 0.f) ? v : v * p1l[ocb + r];
            ov[r] = (__bf16)((v - PM) * PIS);
        }
        *(bf16x4*)(&H1t[pos * 104 + ocb]) = ov;
    }
    __syncthreads();

    // H2 = cprelu(W2*H1 + b2)  (7 mt x 4 nt), into buf0 (Xt dead)
    for (int tt = wid; tt < 28; tt += 4) {
        int mt = tt >> 2, nt = tt & 3;
        f32x4 a = mfma_tile<3>(W2p, 96, mt, H1t, 104, nt, lane);
        int ocb = mt * 16 + quad4;
        int pos = nt * 16 + l15;
        bf16x4 ov;
#pragma unroll
        for (int r = 0; r < 4; r++) {
            float v = a[r] + b2l[ocb + r];
            v = (v >= 0.f) ? v : v * p2l[ocb + r];
            ov[r] = (__bf16)((v - PM) * PIS);
        }
        *(bf16x4*)(&buf0[pos * 136 + ocb]) = ov;
    }
    // zero H2 pad channels 112..127
    for (int i = t; i < 64 * 16; i += 256) {
        int pos = i >> 4, c = 112 + (i & 15);
        buf0[pos * 136 + c] = (__bf16)0.f;
    }
    __syncthreads();   // also: H1t reads done before OutT overwrites region

    // H3 = WM*H2 + bm  (8 mt x 4 nt) -> OutT[ch][pos] in LDS
    for (int tt = wid; tt < 32; tt += 4) {
        int mt = tt >> 2, nt = tt & 3;
        f32x4 a = mfma_tile<4>(WMp, 128, mt, buf0, 136, nt, lane);
        int ocb = mt * 16 + quad4;
        int pos = nt * 16 + l15;
#pragma unroll
        for (int r = 0; r < 4; r++)
            OutT[(ocb + r) * 72 + pos] = (__bf16)(a[r] + bml[ocb + r]);
    }
    __syncthreads();

    // coalesced OutT -> h3 (bf16x8 per lane, 128B per channel row)
#pragma unroll
    for (int it = 0; it < 4; it++) {
        int lin = it * 256 + t;       // 0..1023
        int ch = lin >> 3, pc = lin & 7;
        bf16x8 v = *(const bf16x8*)(OutT + ch * 72 + pc * 8);
        *(bf16x8*)(h3 + ((size_t)b * 128 + ch) * 8192 + p0 + pc * 8) = v;
    }
}

// ---------------------------------------------------------------- k_gemm
// C[2048,4096] = A[2048,8192](bf16) x B[4096,bstride](bf16, N x K rows)
// 128x128 tile, BK=64 (32KB LDS), split-K via blockIdx.z.
// XOR swizzle: 16B chunk (row, c) of a 64-elem row stored at c ^ (row & 7).
__global__ __launch_bounds__(256, 4) void k_gemm(const __bf16* __restrict__ A,
                                                 const __bf16* __restrict__ B,
                                                 size_t bstride,
                                                 float* __restrict__ C0,
                                                 float* __restrict__ C1,
                                                 int KH)
{
    __shared__ __bf16 la[128 * 64];
    __shared__ __bf16 lb[128 * 64];
    const int t = threadIdx.x;
    const int lane = t & 63;
    const int wid = t >> 6;
    const int tM = blockIdx.y * 128;
    const int tN = blockIdx.x * 128;
    const int kz = blockIdx.z;
    const int k0 = kz * KH;
    float* __restrict__ C = kz ? C1 : C0;
    const int wm2 = (wid & 1) * 64;
    const int wn2 = (wid >> 1) * 64;

    f32x4 acc[4][4];
    const f32x4 zero = {0.f, 0.f, 0.f, 0.f};
#pragma unroll
    for (int i = 0; i < 4; i++)
#pragma unroll
        for (int j = 0; j < 4; j++) acc[i][j] = zero;

    // staging: 4 issues per matrix; issue i covers rows i*32..i*32+31
    const int tr = t >> 3;                    // 0..31
    const int sc = (t & 7) ^ (tr & 7);        // swizzled global chunk
    const __bf16* pA[4];
    const __bf16* pB[4];
#pragma unroll
    for (int i = 0; i < 4; i++) {
        pA[i] = A + (size_t)(tM + i * 32 + tr) * 8192 + k0 + sc * 8;
        pB[i] = B + (size_t)(tN + i * 32 + tr) * bstride + k0 + sc * 8;
    }

    const int l15 = lane & 15;
    const int q = lane >> 4;
    int aoff[4], boff[4];
#pragma unroll
    for (int i = 0; i < 4; i++) {
        int row = wm2 + i * 16 + l15;
        aoff[i] = row * 64 + ((q ^ (row & 7)) * 8);
    }
#pragma unroll
    for (int j = 0; j < 4; j++) {
        int row = wn2 + j * 16 + l15;
        boff[j] = row * 64 + ((q ^ (row & 7)) * 8);
    }

    const int iters = KH >> 6;
    for (int it = 0; it < iters; it++) {
#pragma unroll
        for (int i = 0; i < 4; i++) load_lds16(pA[i], la + (i * 256 + t) * 8);
#pragma unroll
        for (int i = 0; i < 4; i++) load_lds16(pB[i], lb + (i * 256 + t) * 8);
#pragma unroll
        for (int i = 0; i < 4; i++) { pA[i] += 64; pB[i] += 64; }
        __syncthreads();
#pragma unroll
        for (int ks = 0; ks < 2; ks++) {
            bf16x8 af[4], bfr[4];
#pragma unroll
            for (int i = 0; i < 4; i++) af[i]  = *(const bf16x8*)(la + (aoff[i] ^ (ks << 5)));
#pragma unroll
            for (int j = 0; j < 4; j++) bfr[j] = *(const bf16x8*)(lb + (boff[j] ^ (ks << 5)));
#pragma unroll
            for (int i = 0; i < 4; i++)
#pragma unroll
                for (int j = 0; j < 4; j++)
                    acc[i][j] = __builtin_amdgcn_mfma_f32_16x16x32_bf16(af[i], bfr[j], acc[i][j], 0, 0, 0);
        }
        __syncthreads();
    }

    const int quad4 = (lane >> 4) * 4;
#pragma unroll
    for (int i = 0; i < 4; i++) {
        int gm = tM + wm2 + i * 16 + quad4;
#pragma unroll
        for (int j = 0; j < 4; j++) {
            int gn = tN + wn2 + j * 16 + l15;
#pragma unroll
            for (int r = 0; r < 4; r++)
                C[(size_t)(gm + r) * 4096 + gn] = acc[i][j][r];
        }
    }
}

// ---------------------------------------------------------------- k_combine
__global__ __launch_bounds__(256) void k_combine(float* __restrict__ out,
                                                 const float* __restrict__ P1,
                                                 int nsplit,
                                                 const __bf16* __restrict__ s_t,
                                                 const int* __restrict__ idx,
                                                 const int* __restrict__ cnt,
                                                 const float* __restrict__ p3)
{
    __shared__ float sp[64][133];
    const int b = blockIdx.y;
    const int o0 = blockIdx.x * 64;
    const int t = threadIdx.x;

    {
        const int ol = t >> 2;
        const int part = t & 3;
        const int o = o0 + ol;
        const int n = cnt[o];
        float acc[32];
#pragma unroll
        for (int j = 0; j < 32; j++) acc[j] = 0.f;
        for (int k = 0; k < n; k++) {
            const int i = idx[o * 16 + k];
            const __bf16* row = s_t + ((size_t)b * 8192 + i) * 128 + part * 32;
#pragma unroll
            for (int j = 0; j < 32; j += 8) {
                bf16x8 v = *(const bf16x8*)(row + j);
#pragma unroll
                for (int u = 0; u < 8; u++) acc[j + u] += (float)v[u];
            }
        }
#pragma unroll
        for (int j = 0; j < 32; j++) sp[ol][part * 32 + j] = acc[j];
    }
    __syncthreads();

    if (nsplit == 2) {
        for (int rr = 0; rr < 32; rr++) {
            const int c = rr * 4 + (t >> 6);
            const int o = t & 63;
            const size_t oi = ((size_t)b * 128 + c) * 4096 + o0 + o;
            float v = out[oi] + P1[oi];
            const float pw = p3[c];
            float y = (v >= 0.f) ? v : v * pw;
            y = (y - PM) * PIS;
            out[oi] = sp[o][c] * RHALF + y * RHALF;
        }
    } else {
        for (int rr = 0; rr < 32; rr++) {
            const int c = rr * 4 + (t >> 6);
            const int o = t & 63;
            const size_t oi = ((size_t)b * 128 + c) * 4096 + o0 + o;
            float v = out[oi];
            const float pw = p3[c];
            float y = (v >= 0.f) ? v : v * pw;
            y = (y - PM) * PIS;
            out[oi] = sp[o][c] * RHALF + y * RHALF;
        }
    }
}

// ---------------------------------------------------------------- launch
extern "C" void kernel_launch(void* const* d_in, const int* in_sizes, int n_in,
                              void* d_out, int out_size, void* d_ws, size_t ws_size,
                              hipStream_t stream) {
    (void)in_sizes; (void)n_in; (void)out_size;
    const float* x    = (const float*)d_in[0];
    const float* conn = (const float*)d_in[1];
    const float* w1   = (const float*)d_in[2];
    const float* b1   = (const float*)d_in[3];
    const float* p1   = (const float*)d_in[4];
    const float* w2   = (const float*)d_in[5];
    const float* b2   = (const float*)d_in[6];
    const float* p2   = (const float*)d_in[7];
    const float* wm   = (const float*)d_in[8];
    const float* bm   = (const float*)d_in[9];
    const float* p3   = (const float*)d_in[10];
    const float* wsw  = (const float*)d_in[11];
    const float* bs   = (const float*)d_in[12];
    float* out = (float*)d_out;

    char* ws = (char*)d_ws;
    __bf16* h3  = (__bf16*)(ws);                          // 33,554,432 B
    __bf16* s_t = (__bf16*)(ws + 33554432);               // 33,554,432 B
    __bf16* W1p = (__bf16*)(ws + 67108864);               // 12,288
    __bf16* W2p = (__bf16*)(ws + 67108864 + 12288);       // 21,504
    __bf16* WMp = (__bf16*)(ws + 67108864 + 33792);       // 32,768
    __bf16* WSp = (__bf16*)(ws + 67108864 + 66560);       // 16,384
    int* idx = (int*)(ws + 67108864 + 82944);             // 262,144
    int* cnt = (int*)(ws + 67108864 + 82944 + 262144);    // 16,384
    const size_t p1_off    = 67108864 + 82944 + 262144 + 16384;   // 67,470,336
    float* Pk1 = (float*)(ws + p1_off);                   // 33,554,432
    const size_t connb_off = p1_off + 33554432;           // 101,024,768

    __bf16* connb;
    size_t  cstride;
    if (ws_size >= connb_off + (size_t)4096 * 8192 * 2) {
        connb = (__bf16*)(ws + connb_off);
        cstride = 8192;
    } else {
        connb = (__bf16*)const_cast<float*>(conn);
        cstride = 16384;   // bf16 row packed into first half of its fp32 row
    }
    const int nsplit = (ws_size >= p1_off + 33554432) ? 2 : 1;
    const int KH = 8192 / nsplit;

    k_prep<<<32, 256, 0, stream>>>(w1, w2, wm, wsw, W1p, W2p, WMp, WSp);
    k_conv<<<4096, 256, 0, stream>>>(conn, connb, cstride, cnt, idx);
    k_chain<<<dim3(8192 / 64, 16), 256, 0, stream>>>(x, b1, p1, b2, p2, bm, bs,
                                                     W1p, W2p, WMp, WSp, h3, s_t);
    k_gemm<<<dim3(4096 / 128, 2048 / 128, nsplit), 256, 0, stream>>>(h3, connb, cstride,
                                                                     out, Pk1, KH);
    k_combine<<<dim3(4096 / 64, 16), 256, 0, stream>>>(out, Pk1, nsplit, s_t, idx, cnt, p3);
}